// Round 2
// baseline (303.020 us; speedup 1.0000x reference)
//
#include <hip/hip_runtime.h>

#define HH 112
#define WW 112
#define PLANE (HH * WW)   // 12544
#define NVEC (PLANE / 4)  // 3136 float4 per plane
#define CHN 96

// One block per (n,c) 112x112 plane. Special-channel branch is block-uniform.
__global__ __launch_bounds__(256) void contour_kernel(
    const float* __restrict__ x,
    const float* __restrict__ rk,
    const float* __restrict__ bias,
    float* __restrict__ out)
{
    const int plane = blockIdx.x;
    const int c = plane % CHN;
    const size_t base = (size_t)plane * PLANE;
    const float* __restrict__ xp = x + base;
    float* __restrict__ op = out + base;
    const float bc = bias[c];

    // mode: 0 = kernel fully masked (y==0), 1 = vertical (c10),
    //       2 = horizontal (c5), 3 = diagonal (c54/c67)
    int mode = 0;
    if (c == 10) mode = 1;
    else if (c == 5) mode = 2;
    else if (c == 54 || c == 67) mode = 3;

    if (mode == 0) {
        // out = x + bias : pure streaming, 16B/lane
        for (int v = threadIdx.x; v < NVEC; v += 256) {
            float4 p = reinterpret_cast<const float4*>(xp)[v];
            float4 r;
            r.x = p.x + bc; r.y = p.y + bc; r.z = p.z + bc; r.w = p.w + bc;
            reinterpret_cast<float4*>(op)[v] = r;
        }
        return;
    }

    const int idxs[8] = {0, 3, 6, 9, 15, 18, 21, 24};
    float wt[8];
    #pragma unroll
    for (int i = 0; i < 8; ++i) {
        int r_, c_;
        if (mode == 1)      { r_ = idxs[i]; c_ = 12; }
        else if (mode == 2) { r_ = 12;      c_ = idxs[i]; }
        else                { r_ = idxs[i]; c_ = idxs[i]; }
        wt[i] = rk[c * 625 + r_ * 25 + c_];
    }

    for (int v = threadIdx.x; v < NVEC; v += 256) {
        const int e0 = v << 2;
        const int h = e0 / WW;           // all 4 elems share the row (112 % 4 == 0)
        const int w0 = e0 - h * WW;

        float4 p = reinterpret_cast<const float4*>(xp)[v];
        const float xf[4] = {p.x, p.y, p.z, p.w};

        float y[4] = {0.f, 0.f, 0.f, 0.f};
        #pragma unroll
        for (int i = 0; i < 8; ++i) {
            const int o = idxs[i] - 12;  // {-12,-9,-6,-3,3,6,9,12}
            if (mode == 1) {
                const int hr = h + o;
                if (hr >= 0 && hr < HH) {
                    float4 q = *reinterpret_cast<const float4*>(xp + hr * WW + w0);
                    y[0] += wt[i] * q.x; y[1] += wt[i] * q.y;
                    y[2] += wt[i] * q.z; y[3] += wt[i] * q.w;
                }
            } else if (mode == 2) {
                #pragma unroll
                for (int j = 0; j < 4; ++j) {
                    const int wc = w0 + j + o;
                    if (wc >= 0 && wc < WW) y[j] += wt[i] * xp[h * WW + wc];
                }
            } else {
                const int hr = h + o;
                if (hr >= 0 && hr < HH) {
                    #pragma unroll
                    for (int j = 0; j < 4; ++j) {
                        const int wc = w0 + j + o;
                        if (wc >= 0 && wc < WW) y[j] += wt[i] * xp[hr * WW + wc];
                    }
                }
            }
        }

        float4 r;
        r.x = fmaf(xf[0], y[0] + 1.0f, bc);
        r.y = fmaf(xf[1], y[1] + 1.0f, bc);
        r.z = fmaf(xf[2], y[2] + 1.0f, bc);
        r.w = fmaf(xf[3], y[3] + 1.0f, bc);
        reinterpret_cast<float4*>(op)[v] = r;
    }
}

extern "C" void kernel_launch(void* const* d_in, const int* in_sizes, int n_in,
                              void* d_out, int out_size, void* d_ws, size_t ws_size,
                              hipStream_t stream) {
    const float* x    = (const float*)d_in[0];
    const float* rk   = (const float*)d_in[1];
    const float* bias = (const float*)d_in[2];
    float* out        = (float*)d_out;

    const int nplanes = in_sizes[0] / PLANE;  // 64 * 96 = 6144
    contour_kernel<<<nplanes, 256, 0, stream>>>(x, rk, bias, out);
}

// Round 3
// 157.280 us; speedup vs baseline: 1.9266x; 1.9266x over previous
//
#include <hip/hip_runtime.h>

#define HH 112
#define WW 112
#define PLANE (HH * WW)   // 12544
#define NVEC (PLANE / 4)  // 3136 float4 per plane
#define CHN 96
#define W4 (WW / 4)       // 28 float4 per row

// ---------------------------------------------------------------------------
// Kernel A: out = x + bias for the 92 fully-masked channels.
// One block per (n,c) plane; special contour planes exit immediately.
// 12 independent float4 loads in flight per thread -> BW-bound, not latency.
// ---------------------------------------------------------------------------
__global__ __launch_bounds__(256) void stream_kernel(
    const float* __restrict__ x,
    const float* __restrict__ bias,
    float* __restrict__ out)
{
    const int plane = blockIdx.x;
    const int c = plane % CHN;
    if (c == 5 || c == 10 || c == 54 || c == 67) return;

    const float bc = bias[c];
    const float4* __restrict__ xv =
        reinterpret_cast<const float4*>(x) + (size_t)plane * NVEC;
    float4* __restrict__ ov =
        reinterpret_cast<float4*>(out) + (size_t)plane * NVEC;
    const int t = threadIdx.x;

    // NVEC = 3136 = 12*256 + 64
    float4 r[12];
    #pragma unroll
    for (int i = 0; i < 12; ++i) r[i] = xv[t + 256 * i];
    #pragma unroll
    for (int i = 0; i < 12; ++i) {
        float4 q;
        q.x = r[i].x + bc; q.y = r[i].y + bc;
        q.z = r[i].z + bc; q.w = r[i].w + bc;
        ov[t + 256 * i] = q;
    }
    if (t < 64) {
        float4 p = xv[3072 + t];
        float4 q;
        q.x = p.x + bc; q.y = p.y + bc; q.z = p.z + bc; q.w = p.w + bc;
        ov[3072 + t] = q;
    }
}

// ---------------------------------------------------------------------------
// Kernel B: the 4 contour channels (c=10 vertical, c=5 horizontal,
// c=54/67 diagonal). One block per special plane (64 batches x 4 = 256).
// Stage the whole 49 KB plane in LDS, then all stencil taps are LDS reads.
// out = x * (y + 1) + bias.
// ---------------------------------------------------------------------------
__global__ __launch_bounds__(256) void fixup_kernel(
    const float* __restrict__ x,
    const float* __restrict__ rk,
    const float* __restrict__ bias,
    float* __restrict__ out)
{
    __shared__ float lds[PLANE];   // 50176 B

    const int scs[4] = {5, 10, 54, 67};
    const int n = blockIdx.x >> 2;
    const int c = scs[blockIdx.x & 3];
    const int plane = n * CHN + c;
    const float bc = bias[c];

    const float4* __restrict__ xv =
        reinterpret_cast<const float4*>(x) + (size_t)plane * NVEC;
    float4* __restrict__ ov =
        reinterpret_cast<float4*>(out) + (size_t)plane * NVEC;
    float4* lv = reinterpret_cast<float4*>(lds);
    const int t = threadIdx.x;

    for (int v = t; v < NVEC; v += 256) lv[v] = xv[v];

    // mode: 1 = vertical (c10), 2 = horizontal (c5), 3 = diagonal (c54/67)
    const int mode = (c == 10) ? 1 : (c == 5) ? 2 : 3;
    const int idxs[8] = {0, 3, 6, 9, 15, 18, 21, 24};
    float wt[8];
    #pragma unroll
    for (int i = 0; i < 8; ++i) {
        int r_, c_;
        if (mode == 1)      { r_ = idxs[i]; c_ = 12; }
        else if (mode == 2) { r_ = 12;      c_ = idxs[i]; }
        else                { r_ = idxs[i]; c_ = idxs[i]; }
        wt[i] = rk[c * 625 + r_ * 25 + c_];
    }

    __syncthreads();

    for (int v = t; v < NVEC; v += 256) {
        const int h  = v / W4;            // row
        const int v0 = v - h * W4;        // float4 index within row
        const int w0 = v0 * 4;

        const float4 p = lv[v];
        float y[4] = {0.f, 0.f, 0.f, 0.f};

        #pragma unroll
        for (int i = 0; i < 8; ++i) {
            const int o = idxs[i] - 12;   // {-12,-9,-6,-3,3,6,9,12}
            if (mode == 1) {
                const int hr = h + o;
                if (hr >= 0 && hr < HH) {
                    const float4 q = lv[hr * W4 + v0];
                    y[0] += wt[i] * q.x; y[1] += wt[i] * q.y;
                    y[2] += wt[i] * q.z; y[3] += wt[i] * q.w;
                }
            } else if (mode == 2) {
                #pragma unroll
                for (int j = 0; j < 4; ++j) {
                    const int wc = w0 + j + o;
                    if (wc >= 0 && wc < WW) y[j] += wt[i] * lds[h * WW + wc];
                }
            } else {
                const int hr = h + o;
                if (hr >= 0 && hr < HH) {
                    #pragma unroll
                    for (int j = 0; j < 4; ++j) {
                        const int wc = w0 + j + o;
                        if (wc >= 0 && wc < WW) y[j] += wt[i] * lds[hr * WW + wc];
                    }
                }
            }
        }

        float4 r;
        r.x = fmaf(p.x, y[0] + 1.0f, bc);
        r.y = fmaf(p.y, y[1] + 1.0f, bc);
        r.z = fmaf(p.z, y[2] + 1.0f, bc);
        r.w = fmaf(p.w, y[3] + 1.0f, bc);
        ov[v] = r;
    }
}

extern "C" void kernel_launch(void* const* d_in, const int* in_sizes, int n_in,
                              void* d_out, int out_size, void* d_ws, size_t ws_size,
                              hipStream_t stream) {
    const float* x    = (const float*)d_in[0];
    const float* rk   = (const float*)d_in[1];
    const float* bias = (const float*)d_in[2];
    float* out        = (float*)d_out;

    const int nplanes = in_sizes[0] / PLANE;  // 64 * 96 = 6144
    const int nbatch  = nplanes / CHN;        // 64

    stream_kernel<<<nplanes, 256, 0, stream>>>(x, bias, out);
    fixup_kernel<<<nbatch * 4, 256, 0, stream>>>(x, rk, bias, out);
}